// Round 5
// baseline (859.901 us; speedup 1.0000x reference)
//
#include <hip/hip_runtime.h>
#include <stdint.h>

// VQ-VAE forward on MI355X — bf16-MFMA fast path + fp64 rescue for exact np argmin.
// (Round 5 = round 4 resubmitted verbatim: round-4 bench died in container
// acquisition, not in the kernel; source re-audited for fault/hang vectors.)
// z_e: [64, 256, 32, 32] f32 ; emb: [1024, 256] f32
// out: z_q_st (16777216) | loss (1) | perplexity (1) | idx (65536, as float)
//
// Fast path: dists via mfma_f32_16x16x32_bf16 on bf16-rounded inputs (dot err
// sigma ~2e-5, differential ~6e-5). resolve flags rows with fast top-2 gap <=
// 4e-4 (~6.7 sigma) -> full-row fp64 rescore through the np fp32 quantization
// pipeline (round-3-verified logic, unchanged). xnorm/enorm stay np-pairwise.
//
// Big scratch lives in d_out's z_q region (overwritten by epilogue last):
//   out bytes [0, 32MB)       A_hi  bf16[65536][256]  (transposed z_e)
//   out bytes [32MB, 40MB)    top2  u64[8][65536][2]
// ws layout (bytes):
//   [0,      4096)    enorm f32[1024]      [4096,   266240)  xnorm f32[65536]
//   [266240, 528384)  fidx  i32[65536]     [528384, 532480)  counts i32[1024]
//   [532480, 532484)  loss_sum             [532484, 532488)  amb_count
//   [532488, 598024)  amb i32[16384]       [598032, 1122320) B_hi bf16[1024][256]

#define D_DIM   256
#define K_CODES 1024
#define N_ROWS  65536
#define N_ELEM  16777216
#define IDX_OFF 16777218
#define FLAG_MARGIN 4.0e-4f
#define AMB_CAP 16384

typedef short short8 __attribute__((ext_vector_type(8)));
typedef float f32x4  __attribute__((ext_vector_type(4)));

__device__ __forceinline__ unsigned int mono(float s) {
    unsigned int u = __float_as_uint(s);
    return (u & 0x80000000u) ? ~u : (u | 0x80000000u);
}
__device__ __forceinline__ float unmono(unsigned int u) {
    return __uint_as_float((u & 0x80000000u) ? (u & 0x7FFFFFFFu) : ~u);
}
__device__ __forceinline__ unsigned short bf16_rne(float x) {
    unsigned int u = __float_as_uint(x);
    return (unsigned short)((u + 0x7FFFu + ((u >> 16) & 1u)) >> 16);
}
__device__ __forceinline__ void gld16(const void* g, void* l) {
    __builtin_amdgcn_global_load_lds(
        (const __attribute__((address_space(1))) unsigned int*)g,
        (__attribute__((address_space(3))) unsigned int*)l, 16, 0, 0);
}

// ---- A-prep: transpose z_e -> A_hi bf16 row-major; np-pairwise xnorm ----
__launch_bounds__(128)
__global__ void a_prep_kernel(const float* __restrict__ z_e,
                              unsigned short* __restrict__ A_hi,
                              float* __restrict__ xnorm) {
#pragma clang fp contract(off)
    __shared__ float T[32][257];
    __shared__ float H[32][2];
    const int tid = threadIdx.x;
    const int bx = blockIdx.x;                 // 2048 blocks
    const int b = bx >> 5, hw0 = (bx & 31) << 5;
    const float* zb = z_e + (size_t)b * 262144 + hw0;
    #pragma unroll 4
    for (int it = 0; it < 16; ++it) {
        int flat = it * 128 + tid;             // 2048 float4
        int d = flat >> 3;
        int hw4 = (flat & 7) << 2;
        float4 v = *(const float4*)(zb + (size_t)d * 1024 + hw4);
        T[hw4 + 0][d] = v.x; T[hw4 + 1][d] = v.y;
        T[hw4 + 2][d] = v.z; T[hw4 + 3][d] = v.w;
    }
    __syncthreads();
    if (tid < 64) {                            // np pairwise tree per 128-half
        int row = tid >> 1, h = tid & 1;
        const float* q = &T[row][h * 128];
        float r[8];
        #pragma unroll
        for (int j = 0; j < 8; ++j) { float x = q[j]; r[j] = x * x; }
        for (int i = 8; i < 128; i += 8)
            #pragma unroll
            for (int j = 0; j < 8; ++j) { float x = q[i + j]; r[j] = r[j] + x * x; }
        H[row][h] = ((r[0] + r[1]) + (r[2] + r[3])) + ((r[4] + r[5]) + (r[6] + r[7]));
    }
    __syncthreads();
    if (tid < 32) xnorm[b * 1024 + hw0 + tid] = H[tid][0] + H[tid][1];
    {   // convert: thread -> (row, 64-d segment)
        int row = tid >> 2, seg = tid & 3;
        const float* src = &T[row][seg * 64];
        unsigned short* dst = A_hi + ((size_t)(b * 1024 + hw0 + row) * 256 + seg * 64);
        #pragma unroll
        for (int c = 0; c < 8; ++c) {
            unsigned int ub[4];
            #pragma unroll
            for (int p = 0; p < 4; ++p) {
                unsigned int lo = bf16_rne(src[c * 8 + 2 * p]);
                unsigned int hi = bf16_rne(src[c * 8 + 2 * p + 1]);
                ub[p] = lo | (hi << 16);
            }
            *(uint4*)(dst + c * 8) = make_uint4(ub[0], ub[1], ub[2], ub[3]);
        }
    }
}

// ---- emb-prep: np-pairwise enorm + B_hi bf16 ----
__launch_bounds__(256)
__global__ void emb_prep_kernel(const float* __restrict__ emb,
                                float* __restrict__ enorm,
                                unsigned short* __restrict__ B_hi) {
#pragma clang fp contract(off)
    int k = blockIdx.x * 256 + threadIdx.x;
    const float* p = emb + (size_t)k * D_DIM;
    float half[2];
    #pragma unroll
    for (int h = 0; h < 2; ++h) {
        const float* q = p + h * 128;
        float r[8];
        #pragma unroll
        for (int j = 0; j < 8; ++j) { float x = q[j]; r[j] = x * x; }
        for (int i = 8; i < 128; i += 8)
            #pragma unroll
            for (int j = 0; j < 8; ++j) { float x = q[i + j]; r[j] = r[j] + x * x; }
        half[h] = ((r[0] + r[1]) + (r[2] + r[3])) + ((r[4] + r[5]) + (r[6] + r[7]));
    }
    enorm[k] = half[0] + half[1];
    unsigned int* dst = (unsigned int*)(B_hi + (size_t)k * D_DIM);
    for (int d = 0; d < 128; ++d) {
        unsigned int lo = bf16_rne(p[2 * d]), hi = bf16_rne(p[2 * d + 1]);
        dst[d] = lo | (hi << 16);
    }
}

// ---- dist2: bf16 MFMA GEMM, 128x128 tile, per-row top-2 ----
__launch_bounds__(256, 2)
__global__ void dist2_kernel(const unsigned short* __restrict__ A_hi,
                             const unsigned short* __restrict__ B_hi,
                             const float* __restrict__ xnorm,
                             const float* __restrict__ enorm,
                             unsigned long long* __restrict__ top2) {
    __shared__ __align__(16) char smem[16384];            // As 8KB | Bs 8KB
    short* As = (short*)smem;
    short* Bs = (short*)(smem + 8192);
    unsigned long long* red = (unsigned long long*)smem;  // overlay [128][2][2]

    const int tid  = threadIdx.x;
    const int lane = tid & 63, w = tid >> 6;
    const int quad = lane >> 4, l16 = lane & 15;
    const int wr = w >> 1, wc = w & 1;
    const int row0 = blockIdx.x * 128;
    const int n0   = blockIdx.y * 128;

    f32x4 acc[4][4];
    #pragma unroll
    for (int i = 0; i < 4; ++i)
        #pragma unroll
        for (int j = 0; j < 4; ++j) acc[i][j] = (f32x4){0.f, 0.f, 0.f, 0.f};

    const int c0 = 2 * w, c1 = 2 * w + 1;
    const int mr = lane >> 2, kq = (lane & 3) * 8;
    const unsigned short* gA0 = A_hi + ((size_t)(row0 + c0 * 16 + mr) * 256 + kq);
    const unsigned short* gA1 = A_hi + ((size_t)(row0 + c1 * 16 + mr) * 256 + kq);
    const unsigned short* gB0 = B_hi + ((size_t)(n0 + c0 * 16 + mr) * 256 + kq);
    const unsigned short* gB1 = B_hi + ((size_t)(n0 + c1 * 16 + mr) * 256 + kq);
    char* lA0 = smem + c0 * 1024;
    char* lA1 = smem + c1 * 1024;
    char* lB0 = smem + 8192 + c0 * 1024;
    char* lB1 = smem + 8192 + c1 * 1024;

    for (int s = 0; s < 8; ++s) {
        gld16(gA0, lA0); gld16(gA1, lA1);
        gld16(gB0, lB0); gld16(gB1, lB1);
        gA0 += 32; gA1 += 32; gB0 += 32; gB1 += 32;
        __syncthreads();
        short8 af[4], bf[4];
        #pragma unroll
        for (int i = 0; i < 4; ++i)
            af[i] = *(const short8*)(As + (wr * 64 + i * 16 + l16) * 32 + quad * 8);
        #pragma unroll
        for (int j = 0; j < 4; ++j)
            bf[j] = *(const short8*)(Bs + (wc * 64 + j * 16 + l16) * 32 + quad * 8);
        #pragma unroll
        for (int i = 0; i < 4; ++i)
            #pragma unroll
            for (int j = 0; j < 4; ++j)
                acc[i][j] = __builtin_amdgcn_mfma_f32_16x16x32_bf16(af[i], bf[j], acc[i][j], 0, 0, 0);
        __syncthreads();
    }

    // scores + per-row top-2 (np order: fl(xn+en) - 2*dot; 2*dot exact)
    float enj[4];
    #pragma unroll
    for (int j = 0; j < 4; ++j) enj[j] = enorm[n0 + wc * 64 + j * 16 + l16];

    #pragma unroll
    for (int i = 0; i < 4; ++i) {
        #pragma unroll
        for (int r = 0; r < 4; ++r) {
            int rowl = wr * 64 + i * 16 + quad * 4 + r;
            float xn = xnorm[row0 + rowl];
            unsigned long long p1 = ~0ull, p2 = ~0ull;
            #pragma unroll
            for (int j = 0; j < 4; ++j) {
                int n = n0 + wc * 64 + j * 16 + l16;
                float t1 = xn + enj[j];
                float sc = t1 - 2.0f * acc[i][j][r];
                unsigned long long p = ((unsigned long long)mono(sc) << 32) | (unsigned int)n;
                if (p < p1) { p2 = p1; p1 = p; } else if (p < p2) p2 = p;
            }
            #pragma unroll
            for (int m = 1; m < 16; m <<= 1) {
                unsigned long long q1 = __shfl_xor(p1, m, 16);
                unsigned long long q2 = __shfl_xor(p2, m, 16);
                if (q1 < p1) { p2 = (p1 < q2) ? p1 : q2; p1 = q1; }
                else         { p2 = (p2 < q1) ? p2 : q1; }
            }
            if (l16 == 0) {
                red[(rowl * 2 + wc) * 2 + 0] = p1;
                red[(rowl * 2 + wc) * 2 + 1] = p2;
            }
        }
    }
    __syncthreads();
    if (tid < 128) {
        unsigned long long p1 = red[(tid * 2 + 0) * 2 + 0];
        unsigned long long p2 = red[(tid * 2 + 0) * 2 + 1];
        unsigned long long q1 = red[(tid * 2 + 1) * 2 + 0];
        unsigned long long q2 = red[(tid * 2 + 1) * 2 + 1];
        if (q1 < p1) { p2 = (p1 < q2) ? p1 : q2; p1 = q1; }
        else         { p2 = (p2 < q1) ? p2 : q1; }
        size_t o = ((size_t)blockIdx.y * N_ROWS + row0 + tid) * 2;
        top2[o + 0] = p1;
        top2[o + 1] = p2;
    }
}

__global__ void resolve_kernel(const unsigned long long* __restrict__ top2,
                               int* __restrict__ fidx,
                               int* __restrict__ amb,
                               int* __restrict__ amb_count) {
    int row = blockIdx.x * 256 + threadIdx.x;
    unsigned long long p1 = ~0ull, p2 = ~0ull;
    #pragma unroll
    for (int c = 0; c < 8; ++c) {
        size_t o = ((size_t)c * N_ROWS + row) * 2;
        unsigned long long a = top2[o + 0];
        unsigned long long b = top2[o + 1];
        if (a < p1) { p2 = p1; p1 = a; } else if (a < p2) p2 = a;
        if (b < p1) { p2 = p1; p1 = b; } else if (b < p2) p2 = b;
    }
    fidx[row] = (int)(p1 & 0xFFFFFFFFull);
    float s1 = unmono((unsigned int)(p1 >> 32));
    float s2 = unmono((unsigned int)(p2 >> 32));
    if (s2 - s1 <= FLAG_MARGIN) {
        int slot = atomicAdd(amb_count, 1);
        if (slot < AMB_CAP) amb[slot] = row;
    }
}

// Full-row rescore with fp64 dots through the np fp32 quantization pipeline.
// (round-3-verified, source unchanged)
__launch_bounds__(256)
__global__ void rescue_kernel(const float* __restrict__ z_e,
                              const float* __restrict__ emb,
                              const float* __restrict__ xnorm,
                              const float* __restrict__ enorm,
                              const int* __restrict__ amb,
                              const int* __restrict__ amb_count,
                              int* __restrict__ fidx) {
    __shared__ __align__(16) float xs[256];
    __shared__ unsigned long long rmin[256];
    const int tid = threadIdx.x;
    int cnt = *amb_count;
    if (cnt > AMB_CAP) cnt = AMB_CAP;
    for (int e = blockIdx.x; e < cnt; e += gridDim.x) {
        int row = amb[e];
        int b = row >> 10, hw = row & 1023;
        xs[tid] = z_e[(size_t)b * 262144 + (size_t)tid * 1024 + hw];
        __syncthreads();
        float xn = xnorm[row];
        unsigned long long best = ~0ull;
        #pragma unroll
        for (int kk = 0; kk < 4; ++kk) {
            int k = kk * 256 + tid;
            const float* ep = emb + (size_t)k * D_DIM;
            double dot = 0.0;
            for (int d = 0; d < D_DIM; d += 4) {
                float4 ev = *(const float4*)(ep + d);
                float4 xv = *(const float4*)(&xs[d]);
                dot += (double)xv.x * (double)ev.x + (double)xv.y * (double)ev.y
                     + (double)xv.z * (double)ev.z + (double)xv.w * (double)ev.w;
            }
            float d32 = (float)dot;
            float t = xn + enorm[k];
            float s = t - 2.f * d32;
            unsigned long long p = ((unsigned long long)mono(s) << 32) | (unsigned int)k;
            if (p < best) best = p;
        }
        rmin[tid] = best;
        __syncthreads();
        for (int st = 128; st > 0; st >>= 1) {
            if (tid < st && rmin[tid + st] < rmin[tid]) rmin[tid] = rmin[tid + st];
            __syncthreads();
        }
        if (tid == 0) fidx[row] = (int)(rmin[0] & 0xFFFFFFFFull);
        __syncthreads();
    }
}

__global__ void epilogue_kernel(const float* __restrict__ z_e,
                                const float* __restrict__ emb,
                                const int* __restrict__ fidx,
                                float* __restrict__ out,
                                int* __restrict__ counts,
                                float* __restrict__ loss_sum) {
    __shared__ int   kb[64];
    __shared__ float rs[256];
    const int tid = threadIdx.x;
    const int rcb = blockIdx.x;
    const int b   = rcb >> 4;
    const int hw0 = (rcb & 15) << 6;

    if (tid < 64) {
        int k = fidx[rcb * 64 + tid];
        kb[tid] = k;
        out[(size_t)IDX_OFF + (size_t)rcb * 64 + tid] = (float)k;
        atomicAdd(&counts[k], 1);
    }
    __syncthreads();

    const int j = tid & 63, dq = tid >> 6;
    const float* er = emb + (size_t)kb[j] * D_DIM;
    const size_t base = (size_t)b * 262144 + hw0 + j;
    float ls = 0.f;
    #pragma unroll 4
    for (int d = dq; d < D_DIM; d += 4) {
        float zq = er[d];
        size_t off = base + (size_t)d * 1024;
        float x = z_e[off];
        out[off] = zq;
        float df = zq - x;
        ls += df * df;
    }
    rs[tid] = ls;
    __syncthreads();
    for (int s = 128; s > 0; s >>= 1) {
        if (tid < s) rs[tid] += rs[tid + s];
        __syncthreads();
    }
    if (tid == 0) atomicAdd(loss_sum, rs[0]);
}

__global__ void finalize_kernel(const int* __restrict__ counts,
                                const float* __restrict__ loss_sum,
                                float* __restrict__ out) {
    __shared__ float rs[256];
    const int tid = threadIdx.x;
    float s = 0.f;
    for (int k = tid; k < K_CODES; k += 256) {
        float p = (float)counts[k] / 65536.0f;
        s += p * logf(p + 1e-10f);
    }
    rs[tid] = s;
    __syncthreads();
    for (int st = 128; st > 0; st >>= 1) {
        if (tid < st) rs[tid] += rs[tid + st];
        __syncthreads();
    }
    if (tid == 0) {
        out[N_ELEM]     = loss_sum[0] * 1.25f / 16777216.0f;
        out[N_ELEM + 1] = expf(-rs[0]);
    }
}

extern "C" void kernel_launch(void* const* d_in, const int* in_sizes, int n_in,
                              void* d_out, int out_size, void* d_ws, size_t ws_size,
                              hipStream_t stream) {
    const float* z_e = (const float*)d_in[0];
    const float* emb = (const float*)d_in[1];
    float* out = (float*)d_out;
    char*  ws  = (char*)d_ws;

    // big scratch inside d_out (overwritten by epilogue)
    unsigned short*     A_hi = (unsigned short*)d_out;
    unsigned long long* top2 = (unsigned long long*)((char*)d_out + 33554432);

    float*          enorm    = (float*)ws;
    float*          xnorm    = (float*)(ws + 4096);
    int*            fidx     = (int*)(ws + 266240);
    int*            counts   = (int*)(ws + 528384);
    float*          loss_sum = (float*)(ws + 532480);
    int*            amb_cnt  = (int*)(ws + 532484);
    int*            amb      = (int*)(ws + 532488);
    unsigned short* B_hi     = (unsigned short*)(ws + 598032);

    hipMemsetAsync(counts, 0, 4104, stream);   // counts + loss_sum + amb_count

    a_prep_kernel<<<2048, 128, 0, stream>>>(z_e, A_hi, xnorm);
    emb_prep_kernel<<<K_CODES / 256, 256, 0, stream>>>(emb, enorm, B_hi);
    dist2_kernel<<<dim3(N_ROWS / 128, K_CODES / 128), 256, 0, stream>>>(A_hi, B_hi, xnorm, enorm, top2);
    resolve_kernel<<<N_ROWS / 256, 256, 0, stream>>>(top2, fidx, amb, amb_cnt);
    rescue_kernel<<<1024, 256, 0, stream>>>(z_e, emb, xnorm, enorm, amb, amb_cnt, fidx);
    epilogue_kernel<<<N_ROWS / 64, 256, 0, stream>>>(z_e, emb, fidx, out, counts, loss_sum);
    finalize_kernel<<<1, 256, 0, stream>>>(counts, loss_sum, out);
}

// Round 8
// 454.016 us; speedup vs baseline: 1.8940x; 1.8940x over previous
//
#include <hip/hip_runtime.h>
#include <stdint.h>

// VQ-VAE forward on MI355X — bf16-MFMA fast path + fp64 rescue for exact np argmin.
// Round 8: functionally identical to rounds 6/7 (both died in container
// acquisition). Textual changes only (renamed rescue symbol, if-wrapper instead
// of early return, reordered locals) to bust any source-hash-keyed artifact
// cache. Logic byte-equivalent; audit notes in round-7 journal.
//
// z_e: [64, 256, 32, 32] f32 ; emb: [1024, 256] f32
// out: z_q_st (16777216) | loss (1) | perplexity (1) | idx (65536, as float)
//
// Big scratch in d_out's z_q region (overwritten by epilogue last):
//   out bytes [0, 32MB)       A_hi  bf16[65536][256]  (transposed z_e)
//   out bytes [32MB, 40MB)    top2  u64[8][65536][2]
// ws layout (bytes):
//   [0,      4096)    enorm f32[1024]      [4096,   266240)  xnorm f32[65536]
//   [266240, 528384)  fidx  i32[65536]     [528384, 532480)  counts i32[1024]
//   [532480, 532484)  loss_sum             [532484, 532488)  amb_count
//   [532488, 794632)  amb i32[65536]
//   [794752, 1319040) B_hi bf16[1024][256]
//   [1319040,2367616) embT f32[256][1024]

#define D_DIM   256
#define K_CODES 1024
#define N_ROWS  65536
#define N_ELEM  16777216
#define IDX_OFF 16777218
#define FLAG_MARGIN 4.0e-4f
#define AMB_CAP 65536

typedef short short8 __attribute__((ext_vector_type(8)));
typedef float f32x4  __attribute__((ext_vector_type(4)));

__device__ __forceinline__ unsigned int mono(float s) {
    unsigned int u = __float_as_uint(s);
    return (u & 0x80000000u) ? ~u : (u | 0x80000000u);
}
__device__ __forceinline__ float unmono(unsigned int u) {
    return __uint_as_float((u & 0x80000000u) ? (u & 0x7FFFFFFFu) : ~u);
}
__device__ __forceinline__ unsigned short bf16_rne(float x) {
    unsigned int u = __float_as_uint(x);
    return (unsigned short)((u + 0x7FFFu + ((u >> 16) & 1u)) >> 16);
}
__device__ __forceinline__ void gld16(const void* g, void* l) {
    __builtin_amdgcn_global_load_lds(
        (const __attribute__((address_space(1))) unsigned int*)g,
        (__attribute__((address_space(3))) unsigned int*)l, 16, 0, 0);
}

// ---- A-prep: transpose z_e -> A_hi bf16 row-major; np-pairwise xnorm ----
__launch_bounds__(128)
__global__ void a_prep_kernel(const float* __restrict__ z_e,
                              unsigned short* __restrict__ A_hi,
                              float* __restrict__ xnorm) {
#pragma clang fp contract(off)
    __shared__ float T[32][257];
    __shared__ float H[32][2];
    const int tid = threadIdx.x;
    const int bx = blockIdx.x;                 // 2048 blocks
    const int b = bx >> 5, hw0 = (bx & 31) << 5;
    const float* zb = z_e + (size_t)b * 262144 + hw0;
    #pragma unroll 4
    for (int it = 0; it < 16; ++it) {
        int flat = it * 128 + tid;             // 2048 float4
        int d = flat >> 3;
        int hw4 = (flat & 7) << 2;
        float4 v = *(const float4*)(zb + (size_t)d * 1024 + hw4);
        T[hw4 + 0][d] = v.x; T[hw4 + 1][d] = v.y;
        T[hw4 + 2][d] = v.z; T[hw4 + 3][d] = v.w;
    }
    __syncthreads();
    if (tid < 64) {                            // np pairwise tree per 128-half
        int row = tid >> 1, h = tid & 1;
        const float* q = &T[row][h * 128];
        float r[8];
        #pragma unroll
        for (int j = 0; j < 8; ++j) { float x = q[j]; r[j] = x * x; }
        for (int i = 8; i < 128; i += 8)
            #pragma unroll
            for (int j = 0; j < 8; ++j) { float x = q[i + j]; r[j] = r[j] + x * x; }
        H[row][h] = ((r[0] + r[1]) + (r[2] + r[3])) + ((r[4] + r[5]) + (r[6] + r[7]));
    }
    __syncthreads();
    if (tid < 32) xnorm[b * 1024 + hw0 + tid] = H[tid][0] + H[tid][1];
    {   // convert: thread -> (row, 64-d segment)
        int row = tid >> 2, seg = tid & 3;
        const float* src = &T[row][seg * 64];
        unsigned short* dst = A_hi + ((size_t)(b * 1024 + hw0 + row) * 256 + seg * 64);
        #pragma unroll
        for (int c = 0; c < 8; ++c) {
            unsigned int ub[4];
            #pragma unroll
            for (int p = 0; p < 4; ++p) {
                unsigned int lo = bf16_rne(src[c * 8 + 2 * p]);
                unsigned int hi = bf16_rne(src[c * 8 + 2 * p + 1]);
                ub[p] = lo | (hi << 16);
            }
            *(uint4*)(dst + c * 8) = make_uint4(ub[0], ub[1], ub[2], ub[3]);
        }
    }
}

// ---- emb-prep: np-pairwise enorm + B_hi bf16 + embT fp32 (d-major) ----
__launch_bounds__(256)
__global__ void emb_prep_kernel(const float* __restrict__ emb,
                                float* __restrict__ enorm,
                                unsigned short* __restrict__ B_hi,
                                float* __restrict__ embT) {
#pragma clang fp contract(off)
    const int k = blockIdx.x * 256 + threadIdx.x;
    const float* p = emb + (size_t)k * D_DIM;
    float half[2];
    #pragma unroll
    for (int h = 0; h < 2; ++h) {
        const float* q = p + h * 128;
        float r[8];
        #pragma unroll
        for (int j = 0; j < 8; ++j) { float x = q[j]; r[j] = x * x; }
        for (int i = 8; i < 128; i += 8)
            #pragma unroll
            for (int j = 0; j < 8; ++j) { float x = q[i + j]; r[j] = r[j] + x * x; }
        half[h] = ((r[0] + r[1]) + (r[2] + r[3])) + ((r[4] + r[5]) + (r[6] + r[7]));
    }
    enorm[k] = half[0] + half[1];
    unsigned int* dst = (unsigned int*)(B_hi + (size_t)k * D_DIM);
    for (int d = 0; d < 128; ++d) {
        unsigned int lo = bf16_rne(p[2 * d]), hi = bf16_rne(p[2 * d + 1]);
        dst[d] = lo | (hi << 16);
    }
    for (int d = 0; d < D_DIM; ++d)            // coalesced: consecutive k per lane
        embT[(size_t)d * K_CODES + k] = p[d];
}

// ---- dist2: bf16 MFMA GEMM, 128x128 tile, per-row top-2 ----
__launch_bounds__(256, 2)
__global__ void dist2_kernel(const unsigned short* __restrict__ A_hi,
                             const unsigned short* __restrict__ B_hi,
                             const float* __restrict__ xnorm,
                             const float* __restrict__ enorm,
                             unsigned long long* __restrict__ top2) {
    __shared__ __align__(16) char smem[16384];            // As 8KB | Bs 8KB
    short* As = (short*)smem;
    short* Bs = (short*)(smem + 8192);
    unsigned long long* red = (unsigned long long*)smem;  // overlay [128][2][2]

    const int tid  = threadIdx.x;
    const int lane = tid & 63, w = tid >> 6;
    const int quad = lane >> 4, l16 = lane & 15;
    const int wr = w >> 1, wc = w & 1;
    const int row0 = blockIdx.x * 128;
    const int n0   = blockIdx.y * 128;

    f32x4 acc[4][4];
    #pragma unroll
    for (int i = 0; i < 4; ++i)
        #pragma unroll
        for (int j = 0; j < 4; ++j) acc[i][j] = (f32x4){0.f, 0.f, 0.f, 0.f};

    const int c0 = 2 * w, c1 = 2 * w + 1;
    const int mr = lane >> 2, kq = (lane & 3) * 8;
    const unsigned short* gA0 = A_hi + ((size_t)(row0 + c0 * 16 + mr) * 256 + kq);
    const unsigned short* gA1 = A_hi + ((size_t)(row0 + c1 * 16 + mr) * 256 + kq);
    const unsigned short* gB0 = B_hi + ((size_t)(n0 + c0 * 16 + mr) * 256 + kq);
    const unsigned short* gB1 = B_hi + ((size_t)(n0 + c1 * 16 + mr) * 256 + kq);
    char* lA0 = smem + c0 * 1024;
    char* lA1 = smem + c1 * 1024;
    char* lB0 = smem + 8192 + c0 * 1024;
    char* lB1 = smem + 8192 + c1 * 1024;

    for (int s = 0; s < 8; ++s) {
        gld16(gA0, lA0); gld16(gA1, lA1);
        gld16(gB0, lB0); gld16(gB1, lB1);
        gA0 += 32; gA1 += 32; gB0 += 32; gB1 += 32;
        __syncthreads();
        short8 af[4], bf[4];
        #pragma unroll
        for (int i = 0; i < 4; ++i)
            af[i] = *(const short8*)(As + (wr * 64 + i * 16 + l16) * 32 + quad * 8);
        #pragma unroll
        for (int j = 0; j < 4; ++j)
            bf[j] = *(const short8*)(Bs + (wc * 64 + j * 16 + l16) * 32 + quad * 8);
        #pragma unroll
        for (int i = 0; i < 4; ++i)
            #pragma unroll
            for (int j = 0; j < 4; ++j)
                acc[i][j] = __builtin_amdgcn_mfma_f32_16x16x32_bf16(af[i], bf[j], acc[i][j], 0, 0, 0);
        __syncthreads();
    }

    float enj[4];
    #pragma unroll
    for (int j = 0; j < 4; ++j) enj[j] = enorm[n0 + wc * 64 + j * 16 + l16];

    #pragma unroll
    for (int i = 0; i < 4; ++i) {
        #pragma unroll
        for (int r = 0; r < 4; ++r) {
            int rowl = wr * 64 + i * 16 + quad * 4 + r;
            float xn = xnorm[row0 + rowl];
            unsigned long long p1 = ~0ull, p2 = ~0ull;
            #pragma unroll
            for (int j = 0; j < 4; ++j) {
                int n = n0 + wc * 64 + j * 16 + l16;
                float t1 = xn + enj[j];
                float sc = t1 - 2.0f * acc[i][j][r];
                unsigned long long p = ((unsigned long long)mono(sc) << 32) | (unsigned int)n;
                if (p < p1) { p2 = p1; p1 = p; } else if (p < p2) p2 = p;
            }
            #pragma unroll
            for (int m = 1; m < 16; m <<= 1) {
                unsigned long long q1 = __shfl_xor(p1, m, 16);
                unsigned long long q2 = __shfl_xor(p2, m, 16);
                if (q1 < p1) { p2 = (p1 < q2) ? p1 : q2; p1 = q1; }
                else         { p2 = (p2 < q1) ? p2 : q1; }
            }
            if (l16 == 0) {
                red[(rowl * 2 + wc) * 2 + 0] = p1;
                red[(rowl * 2 + wc) * 2 + 1] = p2;
            }
        }
    }
    __syncthreads();
    if (tid < 128) {
        unsigned long long p1 = red[(tid * 2 + 0) * 2 + 0];
        unsigned long long p2 = red[(tid * 2 + 0) * 2 + 1];
        unsigned long long q1 = red[(tid * 2 + 1) * 2 + 0];
        unsigned long long q2 = red[(tid * 2 + 1) * 2 + 1];
        if (q1 < p1) { p2 = (p1 < q2) ? p1 : q2; p1 = q1; }
        else         { p2 = (p2 < q1) ? p2 : q1; }
        size_t o = ((size_t)blockIdx.y * N_ROWS + row0 + tid) * 2;
        top2[o + 0] = p1;
        top2[o + 1] = p2;
    }
}

__global__ void resolve_kernel(const unsigned long long* __restrict__ top2,
                               int* __restrict__ fidx,
                               int* __restrict__ amb,
                               int* __restrict__ amb_count) {
    int row = blockIdx.x * 256 + threadIdx.x;
    unsigned long long p1 = ~0ull, p2 = ~0ull;
    #pragma unroll
    for (int c = 0; c < 8; ++c) {
        size_t o = ((size_t)c * N_ROWS + row) * 2;
        unsigned long long a = top2[o + 0];
        unsigned long long b = top2[o + 1];
        if (a < p1) { p2 = p1; p1 = a; } else if (a < p2) p2 = a;
        if (b < p1) { p2 = p1; p1 = b; } else if (b < p2) p2 = b;
    }
    fidx[row] = (int)(p1 & 0xFFFFFFFFull);
    float s1 = unmono((unsigned int)(p1 >> 32));
    float s2 = unmono((unsigned int)(p2 >> 32));
    if (s2 - s1 <= FLAG_MARGIN) {
        int slot = atomicAdd(amb_count, 1);
        if (slot < AMB_CAP) amb[slot] = row;
    }
}

// ---- rescue (coalesced): 8 rows/group; thread owns 4 consecutive codes;
// embT float4 loads; fp64 dots in-lane; block-min via two LDS stages ----
__launch_bounds__(256)
__global__ void rescue_coal_kernel(const float* __restrict__ z_e,
                                   const float* __restrict__ embT,
                                   const float* __restrict__ xnorm,
                                   const float* __restrict__ enorm,
                                   const int* __restrict__ amb,
                                   const int* __restrict__ amb_count,
                                   int* __restrict__ fidx) {
    __shared__ float xs[8][256];
    __shared__ int rows[8];
    __shared__ unsigned long long pm[8][257];   // [j][tid], padded
    __shared__ unsigned long long pm2[8][8];
    const int tid = threadIdx.x;
    int cnt = *amb_count;
    if (cnt > AMB_CAP) cnt = AMB_CAP;
    if (cnt > 0) {
        const int ngroups = (cnt + 7) >> 3;
        for (int g = blockIdx.x; g < ngroups; g += gridDim.x) {
            if (tid < 8) {
                int e = g * 8 + tid;
                rows[tid] = amb[e < cnt ? e : (cnt - 1)];   // pad with dup (benign)
            }
            __syncthreads();
            {   // stage x rows: thread -> (row j, 8 d-elements)
                const int j = tid >> 5, d0 = (tid & 31) * 8;
                const int row = rows[j];
                const int b = row >> 10, hw = row & 1023;
                const float* zp = z_e + (size_t)b * 262144 + hw;
                #pragma unroll
                for (int i = 0; i < 8; ++i)
                    xs[j][d0 + i] = zp[(size_t)(d0 + i) * 1024];
            }
            __syncthreads();

            double acc[4][8];
            #pragma unroll
            for (int c = 0; c < 4; ++c)
                #pragma unroll
                for (int j = 0; j < 8; ++j) acc[c][j] = 0.0;

            const float* ep = embT + 4 * tid;
            for (int d = 0; d < D_DIM; ++d) {
                float4 ev = *(const float4*)(ep + (size_t)d * K_CODES);
                double e0 = (double)ev.x, e1 = (double)ev.y;
                double e2 = (double)ev.z, e3 = (double)ev.w;
                #pragma unroll
                for (int j = 0; j < 8; ++j) {
                    double xd = (double)xs[j][d];
                    acc[0][j] += xd * e0;
                    acc[1][j] += xd * e1;
                    acc[2][j] += xd * e2;
                    acc[3][j] += xd * e3;
                }
            }

            float xnr[8];
            #pragma unroll
            for (int j = 0; j < 8; ++j) xnr[j] = xnorm[rows[j]];

            unsigned long long mymin[8];
            #pragma unroll
            for (int j = 0; j < 8; ++j) mymin[j] = ~0ull;
            #pragma unroll
            for (int c = 0; c < 4; ++c) {
                const int k = 4 * tid + c;
                const float en = enorm[k];
                #pragma unroll
                for (int j = 0; j < 8; ++j) {
                    float d32 = (float)acc[c][j];
                    float t = xnr[j] + en;
                    float s = t - 2.f * d32;
                    unsigned long long p = ((unsigned long long)mono(s) << 32) | (unsigned int)k;
                    if (p < mymin[j]) mymin[j] = p;
                }
            }
            #pragma unroll
            for (int j = 0; j < 8; ++j) pm[j][tid] = mymin[j];
            __syncthreads();
            if (tid < 64) {
                const int j = tid & 7, part = tid >> 3;   // 8 parts x 32 entries
                unsigned long long m = ~0ull;
                for (int i = 0; i < 32; ++i) {
                    unsigned long long v = pm[j][part * 32 + i];
                    if (v < m) m = v;
                }
                pm2[j][part] = m;
            }
            __syncthreads();
            if (tid < 8) {
                unsigned long long m = ~0ull;
                #pragma unroll
                for (int p = 0; p < 8; ++p) if (pm2[tid][p] < m) m = pm2[tid][p];
                fidx[rows[tid]] = (int)(m & 0xFFFFFFFFull);
            }
            __syncthreads();
        }
    }
}

__global__ void epilogue_kernel(const float* __restrict__ z_e,
                                const float* __restrict__ emb,
                                const int* __restrict__ fidx,
                                float* __restrict__ out,
                                int* __restrict__ counts,
                                float* __restrict__ loss_sum) {
    __shared__ int   kb[64];
    __shared__ float rs[256];
    const int tid = threadIdx.x;
    const int rcb = blockIdx.x;
    const int b   = rcb >> 4;
    const int hw0 = (rcb & 15) << 6;

    if (tid < 64) {
        int k = fidx[rcb * 64 + tid];
        kb[tid] = k;
        out[(size_t)IDX_OFF + (size_t)rcb * 64 + tid] = (float)k;
        atomicAdd(&counts[k], 1);
    }
    __syncthreads();

    const int j = tid & 63, dq = tid >> 6;
    const float* er = emb + (size_t)kb[j] * D_DIM;
    const size_t base = (size_t)b * 262144 + hw0 + j;
    float ls = 0.f;
    #pragma unroll 4
    for (int d = dq; d < D_DIM; d += 4) {
        float zq = er[d];
        size_t off = base + (size_t)d * 1024;
        float x = z_e[off];
        out[off] = zq;
        float df = zq - x;
        ls += df * df;
    }
    rs[tid] = ls;
    __syncthreads();
    for (int s = 128; s > 0; s >>= 1) {
        if (tid < s) rs[tid] += rs[tid + s];
        __syncthreads();
    }
    if (tid == 0) atomicAdd(loss_sum, rs[0]);
}

__global__ void finalize_kernel(const int* __restrict__ counts,
                                const float* __restrict__ loss_sum,
                                float* __restrict__ out) {
    __shared__ float rs[256];
    const int tid = threadIdx.x;
    float s = 0.f;
    for (int k = tid; k < K_CODES; k += 256) {
        float p = (float)counts[k] / 65536.0f;
        s += p * logf(p + 1e-10f);
    }
    rs[tid] = s;
    __syncthreads();
    for (int st = 128; st > 0; st >>= 1) {
        if (tid < st) rs[tid] += rs[tid + st];
        __syncthreads();
    }
    if (tid == 0) {
        out[N_ELEM]     = loss_sum[0] * 1.25f / 16777216.0f;
        out[N_ELEM + 1] = expf(-rs[0]);
    }
}

extern "C" void kernel_launch(void* const* d_in, const int* in_sizes, int n_in,
                              void* d_out, int out_size, void* d_ws, size_t ws_size,
                              hipStream_t stream) {
    const float* z_e = (const float*)d_in[0];
    const float* emb = (const float*)d_in[1];
    float* out = (float*)d_out;
    char*  ws  = (char*)d_ws;

    // big scratch inside d_out (overwritten by epilogue)
    unsigned short*     A_hi = (unsigned short*)d_out;
    unsigned long long* top2 = (unsigned long long*)((char*)d_out + 33554432);

    float*          enorm    = (float*)ws;
    float*          xnorm    = (float*)(ws + 4096);
    int*            fidx     = (int*)(ws + 266240);
    int*            counts   = (int*)(ws + 528384);
    float*          loss_sum = (float*)(ws + 532480);
    int*            amb_cnt  = (int*)(ws + 532484);
    int*            amb      = (int*)(ws + 532488);
    unsigned short* B_hi     = (unsigned short*)(ws + 794752);
    float*          embT     = (float*)(ws + 1319040);

    hipMemsetAsync(counts, 0, 4104, stream);   // counts + loss_sum + amb_count

    a_prep_kernel<<<2048, 128, 0, stream>>>(z_e, A_hi, xnorm);
    emb_prep_kernel<<<K_CODES / 256, 256, 0, stream>>>(emb, enorm, B_hi, embT);
    dist2_kernel<<<dim3(N_ROWS / 128, K_CODES / 128), 256, 0, stream>>>(A_hi, B_hi, xnorm, enorm, top2);
    resolve_kernel<<<N_ROWS / 256, 256, 0, stream>>>(top2, fidx, amb, amb_cnt);
    rescue_coal_kernel<<<1024, 256, 0, stream>>>(z_e, embT, xnorm, enorm, amb, amb_cnt, fidx);
    epilogue_kernel<<<N_ROWS / 64, 256, 0, stream>>>(z_e, emb, fidx, out, counts, loss_sum);
    finalize_kernel<<<1, 256, 0, stream>>>(counts, loss_sum, out);
}